// Round 6
// baseline (456.485 us; speedup 1.0000x reference)
//
#include <hip/hip_runtime.h>
#include <hip/hip_bf16.h>
#include <cstdint>

#define D_IN 128
#define DK 32
#define NH 8
#define HD 256   // NH*DK

typedef __attribute__((ext_vector_type(8))) short short8;
typedef __attribute__((ext_vector_type(4))) float f32x4;

__device__ inline float bf2f(unsigned short u) {
  union { unsigned int i; float f; } c;
  c.i = ((unsigned int)u) << 16;
  return c.f;
}
__device__ inline short f2bf(float f) {
  union { float f; unsigned int i; } c; c.f = f;
  unsigned int u = c.i;
  u = u + 0x7FFFu + ((u >> 16) & 1u);  // RNE
  return (short)(u >> 16);
}

// ---------- prep B: Wcat[128][768] -> bf16 MFMA B-fragments ----------
__global__ __launch_bounds__(256) void prep_w_kernel(
    const float* __restrict__ WQ, const float* __restrict__ WK,
    const float* __restrict__ WV, short8* __restrict__ Bbuf) {
  int ct = blockIdx.x;  // 0..47
  int t = threadIdx.x;
  int kt = t >> 6, L = t & 63;
  int col = ct * 16 + (L & 15);
  int type = col >> 8;
  const float* W = (type == 0) ? WQ : (type == 1) ? WK : WV;
  int head = (col & 255) >> 5;
  int kk = col & 31;
  int k0 = kt * 32 + ((L >> 4) << 3);
  short8 o;
  #pragma unroll
  for (int r = 0; r < 8; r++)
    o[r] = f2bf(W[head * (D_IN * DK) + (k0 + r) * DK + kk]);
  Bbuf[(size_t)(ct * 4 + kt) * 64 + L] = o;
}

// ---------- MFMA GEMM (h conversion fused): one block per 16-node tile ----------
__global__ __launch_bounds__(256) void gemm_qkv_kernel(
    const float* __restrict__ h, const short8* __restrict__ Bbuf,
    __hip_bfloat16* __restrict__ Q, __hip_bfloat16* __restrict__ K,
    __hip_bfloat16* __restrict__ V, int nt_total) {
  __shared__ float hs[16][132];   // +4 pad: conflict-free fragment reads
  __shared__ short lds[16][768];
  int nt = blockIdx.x;
  int t = threadIdx.x;
  {
    const float4* h4 = (const float4*)(h + (size_t)nt * 16 * 128);
    float4 v0 = h4[t * 2], v1 = h4[t * 2 + 1];
    int node = t >> 4, dim = (t & 15) * 8;
    hs[node][dim + 0] = v0.x; hs[node][dim + 1] = v0.y;
    hs[node][dim + 2] = v0.z; hs[node][dim + 3] = v0.w;
    hs[node][dim + 4] = v1.x; hs[node][dim + 5] = v1.y;
    hs[node][dim + 6] = v1.z; hs[node][dim + 7] = v1.w;
  }
  __syncthreads();
  int w = t >> 6;
  int L = t & 63;
  int arow = L & 15, k0base = ((L >> 4) << 3);
  short8 afrag[4];
  #pragma unroll
  for (int kt = 0; kt < 4; kt++) {
    #pragma unroll
    for (int r = 0; r < 8; r++)
      afrag[kt][r] = f2bf(hs[arow][kt * 32 + k0base + r]);
  }
  f32x4 acc[12];
  #pragma unroll
  for (int c = 0; c < 12; c++) acc[c] = (f32x4){0.f, 0.f, 0.f, 0.f};
  #pragma unroll
  for (int kt = 0; kt < 4; kt++) {
    #pragma unroll
    for (int c = 0; c < 12; c++) {
      short8 b = Bbuf[(size_t)((w * 12 + c) * 4 + kt) * 64 + L];
      acc[c] = __builtin_amdgcn_mfma_f32_16x16x32_bf16(afrag[kt], b, acc[c], 0, 0, 0);
    }
  }
  int row0 = (L >> 4) << 2;
  int col0 = w * 192 + (L & 15);
  #pragma unroll
  for (int c = 0; c < 12; c++) {
    #pragma unroll
    for (int r = 0; r < 4; r++)
      lds[row0 + r][col0 + c * 16] = f2bf(acc[c][r]);
  }
  __syncthreads();
  __hip_bfloat16* dst[3] = {Q, K, V};
  #pragma unroll
  for (int s = 0; s < 3; s++) {
    char* base = (char*)(dst[s] + (size_t)nt * 16 * HD);
    #pragma unroll
    for (int j = 0; j < 2; j++) {
      int u = t + j * 256;        // 512 16B-units per section
      int row = u >> 5, uc = u & 31;
      float4 vdat = *(const float4*)((const char*)&lds[row][0] + s * 512 + uc * 16);
      *(float4*)(base + row * 512 + uc * 16) = vdat;
    }
  }
}

// ---------------- CSR build ----------------
__global__ void rank_kernel(const int* __restrict__ row, int n_edge,
                            int* __restrict__ cnt, int* __restrict__ rank) {
  int i = blockIdx.x * blockDim.x + threadIdx.x;
  if (i < n_edge) rank[i] = atomicAdd(&cnt[row[i]], 1);
}

__global__ __launch_bounds__(256) void scan1_kernel(
    const int* __restrict__ cnt, int n, int* __restrict__ exc,
    int* __restrict__ bsum) {
  __shared__ int s[256];
  int gid = blockIdx.x * 256 + threadIdx.x;
  int v = (gid < n) ? cnt[gid] : 0;
  s[threadIdx.x] = v;
  __syncthreads();
  #pragma unroll
  for (int off = 1; off < 256; off <<= 1) {
    int t = (threadIdx.x >= off) ? s[threadIdx.x - off] : 0;
    __syncthreads();
    s[threadIdx.x] += t;
    __syncthreads();
  }
  if (gid < n) exc[gid] = s[threadIdx.x] - v;
  if (threadIdx.x == 255) bsum[blockIdx.x] = s[255];
}

__global__ __launch_bounds__(256) void scan2_kernel(int* __restrict__ bsum,
                                                    int nb) {
  __shared__ int s[256];
  int v = (threadIdx.x < nb) ? bsum[threadIdx.x] : 0;
  s[threadIdx.x] = v;
  __syncthreads();
  #pragma unroll
  for (int off = 1; off < 256; off <<= 1) {
    int t = (threadIdx.x >= off) ? s[threadIdx.x - off] : 0;
    __syncthreads();
    s[threadIdx.x] += t;
    __syncthreads();
  }
  if (threadIdx.x < nb) bsum[threadIdx.x] = s[threadIdx.x] - v;
}

__global__ __launch_bounds__(256) void scan3_kernel(
    int* __restrict__ exc, const int* __restrict__ bsum, int n, int n_edge) {
  int gid = blockIdx.x * 256 + threadIdx.x;
  if (gid < n) exc[gid] = exc[gid] + bsum[blockIdx.x];
  if (gid == 0) exc[n] = n_edge;
}

__global__ void scatter_kernel(const int* __restrict__ row,
                               const int* __restrict__ col,
                               const int* __restrict__ rank, int n_edge,
                               const int* __restrict__ offsets,
                               int* __restrict__ col_sorted) {
  int i = blockIdx.x * blockDim.x + threadIdx.x;
  if (i < n_edge) col_sorted[offsets[row[i]] + rank[i]] = col[i];
}

// ---------------- Attention: wave-autonomous, zero LDS, zero barriers ----------------
// Each 32-lane half-wave owns (node, head). Chunk = 32 edges; col + logit live
// in registers; softmax reduce via shfl_xor(w=32); V-phase broadcasts via shfl.
#define ACHUNK 32
__global__ __launch_bounds__(256) void attn_kernel(
    const __hip_bfloat16* __restrict__ Q, const __hip_bfloat16* __restrict__ K,
    const __hip_bfloat16* __restrict__ V, const int* __restrict__ offsets,
    const int* __restrict__ col_sorted, float* __restrict__ out, int n_node) {
  int wave = threadIdx.x >> 6;
  int lane = threadIdx.x & 63;
  int sub = lane & 31;
  int head = wave * 2 + (lane >> 5);

  for (int node = blockIdx.x; node < n_node; node += gridDim.x) {
    int start = offsets[node], end = offsets[node + 1];
    // Q fragment for this head (broadcast: all 32 lanes read the same 64B)
    float qf[32];
    {
      const short8* qp = (const short8*)(Q + (size_t)node * HD + head * 32);
      #pragma unroll
      for (int i = 0; i < 4; i++) {
        short8 qv = qp[i];
        #pragma unroll
        for (int r = 0; r < 8; r++) qf[i * 8 + r] = bf2f((unsigned short)qv[r]);
      }
    }
    float m = -INFINITY, denom = 0.f, acc = 0.f;
    for (int base = start; base < end; base += ACHUNK) {
      int n = min(ACHUNK, end - base);
      int colr = 0;
      float e = -INFINITY;
      if (sub < n) {
        colr = col_sorted[base + sub];
        const short8* kp = (const short8*)(K + (size_t)colr * HD + head * 32);
        float d = 0.f;
        #pragma unroll
        for (int i = 0; i < 4; i++) {
          short8 kv = kp[i];
          #pragma unroll
          for (int r = 0; r < 8; r++)
            d += qf[i * 8 + r] * bf2f((unsigned short)kv[r]);
        }
        e = d * 0.17677669529663687f;  // 1/sqrt(32)
      }
      float lmax = e;
      #pragma unroll
      for (int off = 16; off; off >>= 1)
        lmax = fmaxf(lmax, __shfl_xor(lmax, off, 32));
      float nm = fmaxf(m, lmax);
      float scale = __expf(m - nm);  // first chunk: exp(-inf)=0
      denom *= scale;
      acc *= scale;
      float ex = (sub < n) ? __expf(e - nm) : 0.f;
      float lsum = ex;
      #pragma unroll
      for (int off = 16; off; off >>= 1)
        lsum += __shfl_xor(lsum, off, 32);
      denom += lsum;
      m = nm;
      // V phase: broadcast (w, col) from lane j; 4 independent FMA chains.
      const __hip_bfloat16* vb = V + head * 32 + sub;
      float a0 = 0.f, a1 = 0.f, a2 = 0.f, a3 = 0.f;
      int j = 0;
      for (; j + 4 <= n; j += 4) {
        float w0 = __shfl(ex, j, 32);     int c0 = __shfl(colr, j, 32);
        float w1 = __shfl(ex, j + 1, 32); int c1 = __shfl(colr, j + 1, 32);
        float w2 = __shfl(ex, j + 2, 32); int c2 = __shfl(colr, j + 2, 32);
        float w3 = __shfl(ex, j + 3, 32); int c3 = __shfl(colr, j + 3, 32);
        float v0 = bf2f(*(const unsigned short*)(vb + (size_t)c0 * HD));
        float v1 = bf2f(*(const unsigned short*)(vb + (size_t)c1 * HD));
        float v2 = bf2f(*(const unsigned short*)(vb + (size_t)c2 * HD));
        float v3 = bf2f(*(const unsigned short*)(vb + (size_t)c3 * HD));
        a0 += w0 * v0; a1 += w1 * v1; a2 += w2 * v2; a3 += w3 * v3;
      }
      for (; j < n; j++) {
        float w = __shfl(ex, j, 32);
        int c = __shfl(colr, j, 32);
        a0 += w * bf2f(*(const unsigned short*)(vb + (size_t)c * HD));
      }
      acc += (a0 + a1) + (a2 + a3);
    }
    out[(size_t)node * HD + head * 32 + sub] = (end > start) ? acc / denom : 0.f;
  }
}

extern "C" void kernel_launch(void* const* d_in, const int* in_sizes, int n_in,
                              void* d_out, int out_size, void* d_ws,
                              size_t ws_size, hipStream_t stream) {
  const float* h = (const float*)d_in[0];
  const int* edge = (const int*)d_in[1];
  const float* WQ = (const float*)d_in[2];
  const float* WK = (const float*)d_in[3];
  const float* WV = (const float*)d_in[4];
  float* out = (float*)d_out;

  int n_node = in_sizes[0] / D_IN;
  int n_edge = in_sizes[1] / 2;
  const int* row = edge;
  const int* col = edge + n_edge;

  char* ws = (char*)d_ws;
  size_t off = 0;
  auto alloc = [&](size_t bytes) {
    void* p = ws + off;
    off += (bytes + 255) & ~(size_t)255;
    return p;
  };
  int nt_total = (n_node + 15) / 16;  // 3125 (50000 = 3125*16 exactly)
  __hip_bfloat16* Q = (__hip_bfloat16*)alloc((size_t)nt_total * 16 * HD * 2);
  __hip_bfloat16* K = (__hip_bfloat16*)alloc((size_t)nt_total * 16 * HD * 2);
  __hip_bfloat16* V = (__hip_bfloat16*)alloc((size_t)nt_total * 16 * HD * 2);
  short8* Bbuf = (short8*)alloc((size_t)48 * 4 * 64 * 16);
  int* col_sorted = (int*)alloc((size_t)n_edge * 4);
  int* rank = (int*)alloc((size_t)n_edge * 4);
  int* cnt = (int*)alloc((size_t)n_node * 4);
  int* offsets = (int*)alloc((size_t)(n_node + 1) * 4);
  int* bsum = (int*)alloc(256 * 4);

  hipMemsetAsync(cnt, 0, (size_t)n_node * 4, stream);

  prep_w_kernel<<<48, 256, 0, stream>>>(WQ, WK, WV, Bbuf);
  gemm_qkv_kernel<<<nt_total, 256, 0, stream>>>(h, Bbuf, Q, K, V, nt_total);

  int nb_e = (n_edge + 255) / 256;
  rank_kernel<<<nb_e, 256, 0, stream>>>(row, n_edge, cnt, rank);

  int nb = (n_node + 255) / 256;
  scan1_kernel<<<nb, 256, 0, stream>>>(cnt, n_node, offsets, bsum);
  scan2_kernel<<<1, 256, 0, stream>>>(bsum, nb);
  scan3_kernel<<<nb, 256, 0, stream>>>(offsets, bsum, n_node, n_edge);

  scatter_kernel<<<nb_e, 256, 0, stream>>>(row, col, rank, n_edge, offsets,
                                           col_sorted);

  attn_kernel<<<8192, 256, 0, stream>>>(Q, K, V, offsets, col_sorted, out,
                                        n_node);
}

// Round 7
// 379.523 us; speedup vs baseline: 1.2028x; 1.2028x over previous
//
#include <hip/hip_runtime.h>
#include <hip/hip_bf16.h>
#include <cstdint>

#define D_IN 128
#define DK 32
#define NH 8
#define HD 256   // NH*DK

typedef __attribute__((ext_vector_type(8))) short short8;
typedef __attribute__((ext_vector_type(4))) float f32x4;

__device__ inline float bf2f(unsigned short u) {
  union { unsigned int i; float f; } c;
  c.i = ((unsigned int)u) << 16;
  return c.f;
}
__device__ inline short f2bf(float f) {
  union { float f; unsigned int i; } c; c.f = f;
  unsigned int u = c.i;
  u = u + 0x7FFFu + ((u >> 16) & 1u);  // RNE
  return (short)(u >> 16);
}

// ---------- prep B: Wcat[128][768] -> bf16 MFMA B-fragments ----------
__global__ __launch_bounds__(256) void prep_w_kernel(
    const float* __restrict__ WQ, const float* __restrict__ WK,
    const float* __restrict__ WV, short8* __restrict__ Bbuf) {
  int ct = blockIdx.x;  // 0..47
  int t = threadIdx.x;
  int kt = t >> 6, L = t & 63;
  int col = ct * 16 + (L & 15);
  int type = col >> 8;
  const float* W = (type == 0) ? WQ : (type == 1) ? WK : WV;
  int head = (col & 255) >> 5;
  int kk = col & 31;
  int k0 = kt * 32 + ((L >> 4) << 3);
  short8 o;
  #pragma unroll
  for (int r = 0; r < 8; r++)
    o[r] = f2bf(W[head * (D_IN * DK) + (k0 + r) * DK + kk]);
  Bbuf[(size_t)(ct * 4 + kt) * 64 + L] = o;
}

// ---------- MFMA GEMM (h conversion fused): one block per 16-node tile ----------
__global__ __launch_bounds__(256) void gemm_qkv_kernel(
    const float* __restrict__ h, const short8* __restrict__ Bbuf,
    __hip_bfloat16* __restrict__ Q, __hip_bfloat16* __restrict__ K,
    __hip_bfloat16* __restrict__ V, int nt_total) {
  __shared__ float hs[16][132];   // +4 pad: conflict-free fragment reads
  __shared__ short lds[16][768];
  int nt = blockIdx.x;
  int t = threadIdx.x;
  {
    const float4* h4 = (const float4*)(h + (size_t)nt * 16 * 128);
    float4 v0 = h4[t * 2], v1 = h4[t * 2 + 1];
    int node = t >> 4, dim = (t & 15) * 8;
    hs[node][dim + 0] = v0.x; hs[node][dim + 1] = v0.y;
    hs[node][dim + 2] = v0.z; hs[node][dim + 3] = v0.w;
    hs[node][dim + 4] = v1.x; hs[node][dim + 5] = v1.y;
    hs[node][dim + 6] = v1.z; hs[node][dim + 7] = v1.w;
  }
  __syncthreads();
  int w = t >> 6;
  int L = t & 63;
  int arow = L & 15, k0base = ((L >> 4) << 3);
  short8 afrag[4];
  #pragma unroll
  for (int kt = 0; kt < 4; kt++) {
    #pragma unroll
    for (int r = 0; r < 8; r++)
      afrag[kt][r] = f2bf(hs[arow][kt * 32 + k0base + r]);
  }
  f32x4 acc[12];
  #pragma unroll
  for (int c = 0; c < 12; c++) acc[c] = (f32x4){0.f, 0.f, 0.f, 0.f};
  #pragma unroll
  for (int kt = 0; kt < 4; kt++) {
    #pragma unroll
    for (int c = 0; c < 12; c++) {
      short8 b = Bbuf[(size_t)((w * 12 + c) * 4 + kt) * 64 + L];
      acc[c] = __builtin_amdgcn_mfma_f32_16x16x32_bf16(afrag[kt], b, acc[c], 0, 0, 0);
    }
  }
  int row0 = (L >> 4) << 2;
  int col0 = w * 192 + (L & 15);
  #pragma unroll
  for (int c = 0; c < 12; c++) {
    #pragma unroll
    for (int r = 0; r < 4; r++)
      lds[row0 + r][col0 + c * 16] = f2bf(acc[c][r]);
  }
  __syncthreads();
  __hip_bfloat16* dst[3] = {Q, K, V};
  #pragma unroll
  for (int s = 0; s < 3; s++) {
    char* base = (char*)(dst[s] + (size_t)nt * 16 * HD);
    #pragma unroll
    for (int j = 0; j < 2; j++) {
      int u = t + j * 256;        // 512 16B-units per section
      int row = u >> 5, uc = u & 31;
      float4 vdat = *(const float4*)((const char*)&lds[row][0] + s * 512 + uc * 16);
      *(float4*)(base + row * 512 + uc * 16) = vdat;
    }
  }
}

// ---------------- CSR build ----------------
__global__ void rank_kernel(const int* __restrict__ row, int n_edge,
                            int* __restrict__ cnt, int* __restrict__ rank) {
  int i = blockIdx.x * blockDim.x + threadIdx.x;
  if (i < n_edge) rank[i] = atomicAdd(&cnt[row[i]], 1);
}

__global__ __launch_bounds__(256) void scan1_kernel(
    const int* __restrict__ cnt, int n, int* __restrict__ exc,
    int* __restrict__ bsum) {
  __shared__ int s[256];
  int gid = blockIdx.x * 256 + threadIdx.x;
  int v = (gid < n) ? cnt[gid] : 0;
  s[threadIdx.x] = v;
  __syncthreads();
  #pragma unroll
  for (int off = 1; off < 256; off <<= 1) {
    int t = (threadIdx.x >= off) ? s[threadIdx.x - off] : 0;
    __syncthreads();
    s[threadIdx.x] += t;
    __syncthreads();
  }
  if (gid < n) exc[gid] = s[threadIdx.x] - v;
  if (threadIdx.x == 255) bsum[blockIdx.x] = s[255];
}

__global__ __launch_bounds__(256) void scan2_kernel(int* __restrict__ bsum,
                                                    int nb) {
  __shared__ int s[256];
  int v = (threadIdx.x < nb) ? bsum[threadIdx.x] : 0;
  s[threadIdx.x] = v;
  __syncthreads();
  #pragma unroll
  for (int off = 1; off < 256; off <<= 1) {
    int t = (threadIdx.x >= off) ? s[threadIdx.x - off] : 0;
    __syncthreads();
    s[threadIdx.x] += t;
    __syncthreads();
  }
  if (threadIdx.x < nb) bsum[threadIdx.x] = s[threadIdx.x] - v;
}

__global__ __launch_bounds__(256) void scan3_kernel(
    int* __restrict__ exc, const int* __restrict__ bsum, int n, int n_edge) {
  int gid = blockIdx.x * 256 + threadIdx.x;
  if (gid < n) exc[gid] = exc[gid] + bsum[blockIdx.x];
  if (gid == 0) exc[n] = n_edge;
}

__global__ void scatter_kernel(const int* __restrict__ row,
                               const int* __restrict__ col,
                               const int* __restrict__ rank, int n_edge,
                               const int* __restrict__ offsets,
                               int* __restrict__ col_sorted) {
  int i = blockIdx.x * blockDim.x + threadIdx.x;
  if (i < n_edge) col_sorted[offsets[row[i]] + rank[i]] = col[i];
}

// ---------------- Attention: one WAVE per node, whole wave per edge ----------------
// Lane L owns dims [4L, 4L+4) of the 256-dim concat space (head = L>>3).
// Per edge: ONE coalesced 512B K-row read + ONE 512B V-row read by the wave.
// 8-lane shfl_xor tree -> all 8 head logits simultaneously; branchless online
// softmax fully in registers. No LDS, no barriers.
__global__ __launch_bounds__(256) void attn_kernel(
    const __hip_bfloat16* __restrict__ Q, const __hip_bfloat16* __restrict__ K,
    const __hip_bfloat16* __restrict__ V, const int* __restrict__ offsets,
    const int* __restrict__ col_sorted, float* __restrict__ out, int n_node) {
  int wave = threadIdx.x >> 6;
  int lane = threadIdx.x & 63;
  int node = blockIdx.x * 4 + wave;
  if (node >= n_node) return;
  int start = offsets[node], end = offsets[node + 1];
  int d0 = lane * 4;  // this lane's 4 dims

  float q0, q1, q2, q3;
  {
    ushort4 qv = *(const ushort4*)(Q + (size_t)node * HD + d0);
    q0 = bf2f(qv.x); q1 = bf2f(qv.y); q2 = bf2f(qv.z); q3 = bf2f(qv.w);
  }
  float m = -INFINITY, denom = 0.f;
  float a0 = 0.f, a1 = 0.f, a2 = 0.f, a3 = 0.f;

  for (int e = start; e < end; e += 2) {
    int c0 = col_sorted[e];
    bool has1 = (e + 1 < end);
    int c1 = has1 ? col_sorted[e + 1] : c0;
    // issue all 4 row-loads up front (independent; coalesced 512B each)
    ushort4 k0 = *(const ushort4*)(K + (size_t)c0 * HD + d0);
    ushort4 v0 = *(const ushort4*)(V + (size_t)c0 * HD + d0);
    ushort4 k1 = *(const ushort4*)(K + (size_t)c1 * HD + d0);
    ushort4 v1 = *(const ushort4*)(V + (size_t)c1 * HD + d0);
    // ---- edge 0 ----
    {
      float d = q0 * bf2f(k0.x) + q1 * bf2f(k0.y) + q2 * bf2f(k0.z) +
                q3 * bf2f(k0.w);
      d += __shfl_xor(d, 1);
      d += __shfl_xor(d, 2);
      d += __shfl_xor(d, 4);
      float lg = d * 0.17677669529663687f;  // 1/sqrt(32)
      float nm = fmaxf(m, lg);
      float sc = __expf(m - nm);   // first edge: exp(-inf)=0
      float p = __expf(lg - nm);
      denom = denom * sc + p;
      a0 = a0 * sc + p * bf2f(v0.x);
      a1 = a1 * sc + p * bf2f(v0.y);
      a2 = a2 * sc + p * bf2f(v0.z);
      a3 = a3 * sc + p * bf2f(v0.w);
      m = nm;
    }
    // ---- edge 1 ----
    if (has1) {
      float d = q0 * bf2f(k1.x) + q1 * bf2f(k1.y) + q2 * bf2f(k1.z) +
                q3 * bf2f(k1.w);
      d += __shfl_xor(d, 1);
      d += __shfl_xor(d, 2);
      d += __shfl_xor(d, 4);
      float lg = d * 0.17677669529663687f;
      float nm = fmaxf(m, lg);
      float sc = __expf(m - nm);
      float p = __expf(lg - nm);
      denom = denom * sc + p;
      a0 = a0 * sc + p * bf2f(v1.x);
      a1 = a1 * sc + p * bf2f(v1.y);
      a2 = a2 * sc + p * bf2f(v1.z);
      a3 = a3 * sc + p * bf2f(v1.w);
      m = nm;
    }
  }
  float inv = (end > start) ? 1.f / denom : 0.f;
  float4 o = make_float4(a0 * inv, a1 * inv, a2 * inv, a3 * inv);
  *(float4*)(out + (size_t)node * HD + d0) = o;
}

extern "C" void kernel_launch(void* const* d_in, const int* in_sizes, int n_in,
                              void* d_out, int out_size, void* d_ws,
                              size_t ws_size, hipStream_t stream) {
  const float* h = (const float*)d_in[0];
  const int* edge = (const int*)d_in[1];
  const float* WQ = (const float*)d_in[2];
  const float* WK = (const float*)d_in[3];
  const float* WV = (const float*)d_in[4];
  float* out = (float*)d_out;

  int n_node = in_sizes[0] / D_IN;
  int n_edge = in_sizes[1] / 2;
  const int* row = edge;
  const int* col = edge + n_edge;

  char* ws = (char*)d_ws;
  size_t off = 0;
  auto alloc = [&](size_t bytes) {
    void* p = ws + off;
    off += (bytes + 255) & ~(size_t)255;
    return p;
  };
  int nt_total = (n_node + 15) / 16;  // 3125 (50000 = 3125*16 exactly)
  __hip_bfloat16* Q = (__hip_bfloat16*)alloc((size_t)nt_total * 16 * HD * 2);
  __hip_bfloat16* K = (__hip_bfloat16*)alloc((size_t)nt_total * 16 * HD * 2);
  __hip_bfloat16* V = (__hip_bfloat16*)alloc((size_t)nt_total * 16 * HD * 2);
  short8* Bbuf = (short8*)alloc((size_t)48 * 4 * 64 * 16);
  int* col_sorted = (int*)alloc((size_t)n_edge * 4);
  int* rank = (int*)alloc((size_t)n_edge * 4);
  int* cnt = (int*)alloc((size_t)n_node * 4);
  int* offsets = (int*)alloc((size_t)(n_node + 1) * 4);
  int* bsum = (int*)alloc(256 * 4);

  hipMemsetAsync(cnt, 0, (size_t)n_node * 4, stream);

  prep_w_kernel<<<48, 256, 0, stream>>>(WQ, WK, WV, Bbuf);
  gemm_qkv_kernel<<<nt_total, 256, 0, stream>>>(h, Bbuf, Q, K, V, nt_total);

  int nb_e = (n_edge + 255) / 256;
  rank_kernel<<<nb_e, 256, 0, stream>>>(row, n_edge, cnt, rank);

  int nb = (n_node + 255) / 256;
  scan1_kernel<<<nb, 256, 0, stream>>>(cnt, n_node, offsets, bsum);
  scan2_kernel<<<1, 256, 0, stream>>>(bsum, nb);
  scan3_kernel<<<nb, 256, 0, stream>>>(offsets, bsum, n_node, n_edge);

  scatter_kernel<<<nb_e, 256, 0, stream>>>(row, col, rank, n_edge, offsets,
                                           col_sorted);

  attn_kernel<<<(n_node + 3) / 4, 256, 0, stream>>>(Q, K, V, offsets,
                                                    col_sorted, out, n_node);
}

// Round 8
// 376.929 us; speedup vs baseline: 1.2111x; 1.0069x over previous
//
#include <hip/hip_runtime.h>
#include <hip/hip_bf16.h>
#include <cstdint>

#define D_IN 128
#define DK 32
#define NH 8
#define HD 256   // NH*DK
#define KVW 512  // K row | V row interleaved per node

typedef __attribute__((ext_vector_type(8))) short short8;
typedef __attribute__((ext_vector_type(4))) float f32x4;

__device__ inline float bf2f(unsigned short u) {
  union { unsigned int i; float f; } c;
  c.i = ((unsigned int)u) << 16;
  return c.f;
}
__device__ inline float u2f(unsigned int u) {
  union { unsigned int i; float f; } c; c.i = u; return c.f;
}
__device__ inline short f2bf(float f) {
  union { float f; unsigned int i; } c; c.f = f;
  unsigned int u = c.i;
  u = u + 0x7FFFu + ((u >> 16) & 1u);  // RNE
  return (short)(u >> 16);
}

// ---------- prep B: Wcat[128][768] -> bf16 MFMA B-fragments ----------
__global__ __launch_bounds__(256) void prep_w_kernel(
    const float* __restrict__ WQ, const float* __restrict__ WK,
    const float* __restrict__ WV, short8* __restrict__ Bbuf) {
  int ct = blockIdx.x;  // 0..47
  int t = threadIdx.x;
  int kt = t >> 6, L = t & 63;
  int col = ct * 16 + (L & 15);
  int type = col >> 8;
  const float* W = (type == 0) ? WQ : (type == 1) ? WK : WV;
  int head = (col & 255) >> 5;
  int kk = col & 31;
  int k0 = kt * 32 + ((L >> 4) << 3);
  short8 o;
  #pragma unroll
  for (int r = 0; r < 8; r++)
    o[r] = f2bf(W[head * (D_IN * DK) + (k0 + r) * DK + kk]);
  Bbuf[(size_t)(ct * 4 + kt) * 64 + L] = o;
}

// ---------- MFMA GEMM: one block per 16-node tile; writes Q + interleaved KV ----------
__global__ __launch_bounds__(256) void gemm_qkv_kernel(
    const float* __restrict__ h, const short8* __restrict__ Bbuf,
    __hip_bfloat16* __restrict__ Q, __hip_bfloat16* __restrict__ KV,
    int nt_total) {
  __shared__ float hs[16][132];   // +4 pad: conflict-free fragment reads
  __shared__ short lds[16][768];  // Q 0-255 | K 256-511 | V 512-767
  int nt = blockIdx.x;
  int t = threadIdx.x;
  {
    const float4* h4 = (const float4*)(h + (size_t)nt * 16 * 128);
    float4 v0 = h4[t * 2], v1 = h4[t * 2 + 1];
    int node = t >> 4, dim = (t & 15) * 8;
    hs[node][dim + 0] = v0.x; hs[node][dim + 1] = v0.y;
    hs[node][dim + 2] = v0.z; hs[node][dim + 3] = v0.w;
    hs[node][dim + 4] = v1.x; hs[node][dim + 5] = v1.y;
    hs[node][dim + 6] = v1.z; hs[node][dim + 7] = v1.w;
  }
  __syncthreads();
  int w = t >> 6;
  int L = t & 63;
  int arow = L & 15, k0base = ((L >> 4) << 3);
  short8 afrag[4];
  #pragma unroll
  for (int kt = 0; kt < 4; kt++) {
    #pragma unroll
    for (int r = 0; r < 8; r++)
      afrag[kt][r] = f2bf(hs[arow][kt * 32 + k0base + r]);
  }
  f32x4 acc[12];
  #pragma unroll
  for (int c = 0; c < 12; c++) acc[c] = (f32x4){0.f, 0.f, 0.f, 0.f};
  #pragma unroll
  for (int kt = 0; kt < 4; kt++) {
    #pragma unroll
    for (int c = 0; c < 12; c++) {
      short8 b = Bbuf[(size_t)((w * 12 + c) * 4 + kt) * 64 + L];
      acc[c] = __builtin_amdgcn_mfma_f32_16x16x32_bf16(afrag[kt], b, acc[c], 0, 0, 0);
    }
  }
  int row0 = (L >> 4) << 2;
  int col0 = w * 192 + (L & 15);
  #pragma unroll
  for (int c = 0; c < 12; c++) {
    #pragma unroll
    for (int r = 0; r < 4; r++)
      lds[row0 + r][col0 + c * 16] = f2bf(acc[c][r]);
  }
  __syncthreads();
  // Q out: 512 16B-units, fully coalesced
  #pragma unroll
  for (int j = 0; j < 2; j++) {
    int u = t + j * 256;
    int row = u >> 5, uc = u & 31;
    float4 vdat = *(const float4*)&lds[row][uc * 8];
    *(float4*)(Q + (size_t)(nt * 16 + row) * HD + uc * 8) = vdat;
  }
  // KV out: 1024 16B-units (K cols 256-511 -> KV 0-255; V cols 512-767 -> KV 256-511)
  #pragma unroll
  for (int j = 0; j < 4; j++) {
    int u = t + j * 256;
    int row = u >> 6, uc = u & 63;
    float4 vdat = *(const float4*)&lds[row][256 + uc * 8];
    *(float4*)(KV + (size_t)(nt * 16 + row) * KVW + uc * 8) = vdat;
  }
}

// ---------------- CSR build ----------------
__global__ void rank_kernel(const int* __restrict__ row, int n_edge,
                            int* __restrict__ cnt, int* __restrict__ rank) {
  int i = blockIdx.x * blockDim.x + threadIdx.x;
  if (i < n_edge) rank[i] = atomicAdd(&cnt[row[i]], 1);
}

__global__ __launch_bounds__(256) void scan1_kernel(
    const int* __restrict__ cnt, int n, int* __restrict__ exc,
    int* __restrict__ bsum) {
  __shared__ int s[256];
  int gid = blockIdx.x * 256 + threadIdx.x;
  int v = (gid < n) ? cnt[gid] : 0;
  s[threadIdx.x] = v;
  __syncthreads();
  #pragma unroll
  for (int off = 1; off < 256; off <<= 1) {
    int t = (threadIdx.x >= off) ? s[threadIdx.x - off] : 0;
    __syncthreads();
    s[threadIdx.x] += t;
    __syncthreads();
  }
  if (gid < n) exc[gid] = s[threadIdx.x] - v;
  if (threadIdx.x == 255) bsum[blockIdx.x] = s[255];
}

__global__ __launch_bounds__(256) void scan2_kernel(int* __restrict__ bsum,
                                                    int nb) {
  __shared__ int s[256];
  int v = (threadIdx.x < nb) ? bsum[threadIdx.x] : 0;
  s[threadIdx.x] = v;
  __syncthreads();
  #pragma unroll
  for (int off = 1; off < 256; off <<= 1) {
    int t = (threadIdx.x >= off) ? s[threadIdx.x - off] : 0;
    __syncthreads();
    s[threadIdx.x] += t;
    __syncthreads();
  }
  if (threadIdx.x < nb) bsum[threadIdx.x] = s[threadIdx.x] - v;
}

__global__ __launch_bounds__(256) void scan3_kernel(
    int* __restrict__ exc, const int* __restrict__ bsum, int n, int n_edge) {
  int gid = blockIdx.x * 256 + threadIdx.x;
  if (gid < n) exc[gid] = exc[gid] + bsum[blockIdx.x];
  if (gid == 0) exc[n] = n_edge;
}

__global__ void scatter_kernel(const int* __restrict__ row,
                               const int* __restrict__ col,
                               const int* __restrict__ rank, int n_edge,
                               const int* __restrict__ offsets,
                               int* __restrict__ col_sorted) {
  int i = blockIdx.x * blockDim.x + threadIdx.x;
  if (i < n_edge) col_sorted[offsets[row[i]] + rank[i]] = col[i];
}

// ---------------- Attention: one wave per node, ONE 1KB load per edge ----------------
// KV[node] = [K dims 0-255 | V dims 0-255] bf16 (1KB). Lane l reads bytes
// [16l,16l+16): lanes 0-31 carry K (lane owns 8 K dims), lanes 32-63 carry V.
// head of sub-lane s (=l&31) is s>>2 for both halves. Dot over 4 lanes via
// shfl_xor(1,2); K->V logit transfer via one shfl. Defer-max online softmax
// (threshold 8 nats): common path has no accumulator rescale.
#define AT_PROCESS(r)                                                        \
  {                                                                          \
    float x0 = u2f(r.x << 16), x1 = u2f(r.x & 0xFFFF0000u);                  \
    float x2 = u2f(r.y << 16), x3 = u2f(r.y & 0xFFFF0000u);                  \
    float x4 = u2f(r.z << 16), x5 = u2f(r.z & 0xFFFF0000u);                  \
    float x6 = u2f(r.w << 16), x7 = u2f(r.w & 0xFFFF0000u);                  \
    float d = x0 * qf0;                                                      \
    d = fmaf(x1, qf1, d); d = fmaf(x2, qf2, d); d = fmaf(x3, qf3, d);        \
    d = fmaf(x4, qf4, d); d = fmaf(x5, qf5, d); d = fmaf(x6, qf6, d);        \
    d = fmaf(x7, qf7, d);                                                    \
    d += __shfl_xor(d, 1);                                                   \
    d += __shfl_xor(d, 2);                                                   \
    float lg = __shfl(d, sub);                                               \
    if (__any(lg - m > 8.0f)) {                                              \
      float nm = fmaxf(m, lg);                                               \
      float sc = __expf(m - nm);                                             \
      denom *= sc;                                                           \
      a0 *= sc; a1 *= sc; a2 *= sc; a3 *= sc;                                \
      a4 *= sc; a5 *= sc; a6 *= sc; a7 *= sc;                                \
      m = nm;                                                                \
    }                                                                        \
    float p = __expf(lg - m);                                                \
    denom += p;                                                              \
    a0 = fmaf(p, x0, a0); a1 = fmaf(p, x1, a1);                              \
    a2 = fmaf(p, x2, a2); a3 = fmaf(p, x3, a3);                              \
    a4 = fmaf(p, x4, a4); a5 = fmaf(p, x5, a5);                              \
    a6 = fmaf(p, x6, a6); a7 = fmaf(p, x7, a7);                              \
  }

__global__ __launch_bounds__(256) void attn_kernel(
    const __hip_bfloat16* __restrict__ Q, const __hip_bfloat16* __restrict__ KV,
    const int* __restrict__ offsets, const int* __restrict__ col_sorted,
    float* __restrict__ out, int n_node) {
  int wave = threadIdx.x >> 6;
  int lane = threadIdx.x & 63;
  int sub = lane & 31;
  int node = blockIdx.x * 4 + wave;
  if (node >= n_node) return;
  int start = offsets[node], end = offsets[node + 1];

  // q dims [8*sub, 8*sub+8), prescaled by 1/sqrt(32). (V lanes: unused garbage.)
  const float QS = 0.17677669529663687f;
  float qf0, qf1, qf2, qf3, qf4, qf5, qf6, qf7;
  {
    uint4 qr = *(const uint4*)(Q + (size_t)node * HD + sub * 8);
    qf0 = u2f(qr.x << 16) * QS; qf1 = u2f(qr.x & 0xFFFF0000u) * QS;
    qf2 = u2f(qr.y << 16) * QS; qf3 = u2f(qr.y & 0xFFFF0000u) * QS;
    qf4 = u2f(qr.z << 16) * QS; qf5 = u2f(qr.z & 0xFFFF0000u) * QS;
    qf6 = u2f(qr.w << 16) * QS; qf7 = u2f(qr.w & 0xFFFF0000u) * QS;
  }
  float m = -INFINITY, denom = 0.f;
  float a0 = 0.f, a1 = 0.f, a2 = 0.f, a3 = 0.f;
  float a4 = 0.f, a5 = 0.f, a6 = 0.f, a7 = 0.f;

  const char* kvbase = (const char*)KV + lane * 16;
  int e = start;
  for (; e + 4 <= end; e += 4) {
    int c0 = col_sorted[e], c1 = col_sorted[e + 1];
    int c2 = col_sorted[e + 2], c3 = col_sorted[e + 3];
    uint4 r0 = *(const uint4*)(kvbase + (size_t)c0 * 1024);
    uint4 r1 = *(const uint4*)(kvbase + (size_t)c1 * 1024);
    uint4 r2 = *(const uint4*)(kvbase + (size_t)c2 * 1024);
    uint4 r3 = *(const uint4*)(kvbase + (size_t)c3 * 1024);
    AT_PROCESS(r0);
    AT_PROCESS(r1);
    AT_PROCESS(r2);
    AT_PROCESS(r3);
  }
  for (; e < end; e++) {
    int c = col_sorted[e];
    uint4 r = *(const uint4*)(kvbase + (size_t)c * 1024);
    AT_PROCESS(r);
  }

  float inv = (end > start) ? 1.f / denom : 0.f;
  if (lane >= 32) {
    float* op = out + (size_t)node * HD + sub * 8;
    float4 o0 = make_float4(a0 * inv, a1 * inv, a2 * inv, a3 * inv);
    float4 o1 = make_float4(a4 * inv, a5 * inv, a6 * inv, a7 * inv);
    *(float4*)op = o0;
    *(float4*)(op + 4) = o1;
  }
}

extern "C" void kernel_launch(void* const* d_in, const int* in_sizes, int n_in,
                              void* d_out, int out_size, void* d_ws,
                              size_t ws_size, hipStream_t stream) {
  const float* h = (const float*)d_in[0];
  const int* edge = (const int*)d_in[1];
  const float* WQ = (const float*)d_in[2];
  const float* WK = (const float*)d_in[3];
  const float* WV = (const float*)d_in[4];
  float* out = (float*)d_out;

  int n_node = in_sizes[0] / D_IN;
  int n_edge = in_sizes[1] / 2;
  const int* row = edge;
  const int* col = edge + n_edge;

  char* ws = (char*)d_ws;
  size_t off = 0;
  auto alloc = [&](size_t bytes) {
    void* p = ws + off;
    off += (bytes + 255) & ~(size_t)255;
    return p;
  };
  int nt_total = (n_node + 15) / 16;  // 3125 (50000 = 3125*16 exactly)
  __hip_bfloat16* Q = (__hip_bfloat16*)alloc((size_t)nt_total * 16 * HD * 2);
  __hip_bfloat16* KV = (__hip_bfloat16*)alloc((size_t)nt_total * 16 * KVW * 2);
  short8* Bbuf = (short8*)alloc((size_t)48 * 4 * 64 * 16);
  int* col_sorted = (int*)alloc((size_t)n_edge * 4);
  int* rank = (int*)alloc((size_t)n_edge * 4);
  int* cnt = (int*)alloc((size_t)n_node * 4);
  int* offsets = (int*)alloc((size_t)(n_node + 1) * 4);
  int* bsum = (int*)alloc(256 * 4);

  hipMemsetAsync(cnt, 0, (size_t)n_node * 4, stream);

  prep_w_kernel<<<48, 256, 0, stream>>>(WQ, WK, WV, Bbuf);
  gemm_qkv_kernel<<<nt_total, 256, 0, stream>>>(h, Bbuf, Q, KV, nt_total);

  int nb_e = (n_edge + 255) / 256;
  rank_kernel<<<nb_e, 256, 0, stream>>>(row, n_edge, cnt, rank);

  int nb = (n_node + 255) / 256;
  scan1_kernel<<<nb, 256, 0, stream>>>(cnt, n_node, offsets, bsum);
  scan2_kernel<<<1, 256, 0, stream>>>(bsum, nb);
  scan3_kernel<<<nb, 256, 0, stream>>>(offsets, bsum, n_node, n_edge);

  scatter_kernel<<<nb_e, 256, 0, stream>>>(row, col, rank, n_edge, offsets,
                                           col_sorted);

  attn_kernel<<<(n_node + 3) / 4, 256, 0, stream>>>(Q, KV, offsets, col_sorted,
                                                    out, n_node);
}